// Round 2
// baseline (950.111 us; speedup 1.0000x reference)
//
#include <hip/hip_runtime.h>
#include <cstdint>
#include <cstddef>

#define B_ROWS 8192
#define D_DIM  1024
#define H_DIM  4096
#define O_DIM  1024
#define E_NUM  3

typedef __attribute__((ext_vector_type(4))) float f4;
typedef __attribute__((ext_vector_type(8))) _Float16 half8;

__device__ __forceinline__ unsigned short f2h_bits(float f) {
  _Float16 h = (_Float16)f;
  return __builtin_bit_cast(unsigned short, h);
}

// async global->LDS, 16B per lane. LDS dest = wave-uniform base + lane*16.
__device__ __forceinline__ void async16(const void* g, void* l) {
  __builtin_amdgcn_global_load_lds(
      (const __attribute__((address_space(1))) unsigned int*)g,
      (__attribute__((address_space(3))) unsigned int*)l, 16, 0, 0);
}

// ---------------- cast x (fp32 -> f16), 8 elems/thread ----------------
__global__ __launch_bounds__(256) void k_cast_x(const float* __restrict__ in,
                                                unsigned short* __restrict__ out) {
  size_t i = (size_t)blockIdx.x * 256 + threadIdx.x;
  const f4* p = (const f4*)in;
  f4 a = p[2 * i], b = p[2 * i + 1];
  half8 h;
#pragma unroll
  for (int j = 0; j < 4; ++j) { h[j] = (_Float16)a[j]; h[4 + j] = (_Float16)b[j]; }
  *(half8*)(out + 8 * i) = h;
}

// ------------- transpose + cast: in[e][R][C] f32 -> out[e][C][R] f16 -------------
__global__ __launch_bounds__(256) void k_transpose_cast(const float* __restrict__ in,
                                                        unsigned short* __restrict__ out,
                                                        int R, int C) {
  __shared__ float tile[32][33];
  const size_t eoff = (size_t)blockIdx.z * R * C;
  const float* I = in + eoff;
  unsigned short* O = out + eoff;
  int c0 = blockIdx.x * 32, r0 = blockIdx.y * 32;
  int tx = threadIdx.x & 31, ty = threadIdx.x >> 5;
#pragma unroll
  for (int i = 0; i < 4; ++i)
    tile[ty + 8 * i][tx] = I[(size_t)(r0 + ty + 8 * i) * C + c0 + tx];
  __syncthreads();
#pragma unroll
  for (int i = 0; i < 4; ++i)
    O[(size_t)(c0 + ty + 8 * i) * R + r0 + tx] = f2h_bits(tile[tx][ty + 8 * i]);
}

// ------------- fp32 GEMM + bias + relu (gating layers 1&2) -------------
__global__ __launch_bounds__(256) void k_gemm_f32(const float* __restrict__ A,
                                                  const float* __restrict__ Bm,
                                                  const float* __restrict__ bias,
                                                  float* __restrict__ C,
                                                  int N, int K) {
  __shared__ float sAT[16][68];
  __shared__ float sB[16][68];
  const int t = threadIdx.x;
  const int tx = t & 15, ty = t >> 4;
  const int m0 = blockIdx.y * 64, n0 = blockIdx.x * 64;
  float acc[4][4] = {};
  for (int k0 = 0; k0 < K; k0 += 16) {
    __syncthreads();
#pragma unroll
    for (int i = 0; i < 4; ++i) {
      int idx = t + i * 256;
      int r = idx >> 4, c = idx & 15;
      sAT[c][r] = A[(size_t)(m0 + r) * K + (k0 + c)];
      int rb = idx >> 6, cb = idx & 63;
      sB[rb][cb] = Bm[(size_t)(k0 + rb) * N + (n0 + cb)];
    }
    __syncthreads();
#pragma unroll
    for (int kk = 0; kk < 16; ++kk) {
      f4 av = *(const f4*)&sAT[kk][ty * 4];
      f4 bv = *(const f4*)&sB[kk][tx * 4];
#pragma unroll
      for (int i = 0; i < 4; ++i)
#pragma unroll
        for (int j = 0; j < 4; ++j)
          acc[i][j] = fmaf(av[i], bv[j], acc[i][j]);
    }
  }
#pragma unroll
  for (int i = 0; i < 4; ++i) {
    int row = m0 + ty * 4 + i;
    f4 v;
#pragma unroll
    for (int j = 0; j < 4; ++j)
      v[j] = fmaxf(acc[i][j] + bias[n0 + tx * 4 + j], 0.f);
    *(f4*)&C[(size_t)row * N + n0 + tx * 4] = v;
  }
}

// ------------- gating layer 3 + softmax + top-2 + renorm -------------
__global__ __launch_bounds__(256) void k_gate_topk(const float* __restrict__ h2,
                                                   const float* __restrict__ gw3,
                                                   const float* __restrict__ gb3,
                                                   float* __restrict__ gates,
                                                   float* __restrict__ combine) {
  const int lane = threadIdx.x & 63;
  const int row = blockIdx.x * 4 + (threadIdx.x >> 6);
  const float* h = h2 + (size_t)row * 128;
  float h0 = h[lane], h1 = h[lane + 64];
  float l0 = h0 * gw3[lane * 3 + 0] + h1 * gw3[(lane + 64) * 3 + 0];
  float l1 = h0 * gw3[lane * 3 + 1] + h1 * gw3[(lane + 64) * 3 + 1];
  float l2 = h0 * gw3[lane * 3 + 2] + h1 * gw3[(lane + 64) * 3 + 2];
#pragma unroll
  for (int off = 32; off > 0; off >>= 1) {
    l0 += __shfl_down(l0, off);
    l1 += __shfl_down(l1, off);
    l2 += __shfl_down(l2, off);
  }
  if (lane == 0) {
    float g0 = l0 + gb3[0], g1v = l1 + gb3[1], g2v = l2 + gb3[2];
    float mx = fmaxf(g0, fmaxf(g1v, g2v));
    float e0 = expf(g0 - mx), e1 = expf(g1v - mx), e2 = expf(g2v - mx);
    float inv = 1.f / (e0 + e1 + e2);
    float p0 = e0 * inv, p1 = e1 * inv, p2 = e2 * inv;
    gates[row * 3 + 0] = p0; gates[row * 3 + 1] = p1; gates[row * 3 + 2] = p2;
    // exclude argmin; '<=' so ties exclude the HIGHER index (lax.top_k tie rule)
    int amin = 0; float pm = p0;
    if (p1 <= pm) { pm = p1; amin = 1; }
    if (p2 <= pm) { pm = p2; amin = 2; }
    float denom = (p0 + p1 + p2) - pm;
    combine[row * 3 + 0] = (amin == 0) ? 0.f : p0 / denom;
    combine[row * 3 + 1] = (amin == 1) ? 0.f : p1 / denom;
    combine[row * 3 + 2] = (amin == 2) ? 0.f : p2 / denom;
  }
}

// ---------------- expert GEMM1: ehs = f16(c * relu(x @ w1 + eb1)) ----------------
// 128x128 tile, BK=64, 4 waves (2x2), 16x16x32 f16 MFMA, async LDS staging,
// XOR-swizzled LDS (16B blocks, j ^= row&7) so ds_read_b128 is 2-way max.
__global__ __launch_bounds__(256) void k_expert_h(const unsigned short* __restrict__ Xh,
                                                  const unsigned short* __restrict__ W1T,
                                                  const float* __restrict__ combine,
                                                  const float* __restrict__ eb1,
                                                  unsigned short* __restrict__ EHS,
                                                  int Brows) {
  constexpr int K = D_DIM;  // 1024
  const int e = blockIdx.z;
  const int m0 = blockIdx.y * 128, n0 = blockIdx.x * 128;
  __shared__ __align__(16) char smem[32768];
  __shared__ float sC[128];
  char* sA = smem;
  char* sB = smem + 16384;
  const int t = threadIdx.x;
  if (t < 128) sC[t] = combine[(size_t)(m0 + t) * 3 + e];

  const unsigned short* aptr[4];
  const unsigned short* bptr[4];
  int soff[4];
#pragma unroll
  for (int i = 0; i < 4; ++i) {
    int sa = t + i * 256;
    int row = sa >> 3;
    int j = (sa & 7) ^ (row & 7);
    soff[i] = sa * 16;
    aptr[i] = Xh + (size_t)(m0 + row) * K + j * 8;
    bptr[i] = W1T + (size_t)e * H_DIM * K + (size_t)(n0 + row) * K + j * 8;
  }
  const int lane = t & 63;
  const int wm = (t >> 6) & 1, wn = t >> 7;
  const int quad = lane >> 4, l16 = lane & 15;
  int offA[4][2], offB[4][2];
#pragma unroll
  for (int mt = 0; mt < 4; ++mt) {
    int ra = wm * 64 + mt * 16 + l16;
    int rb = wn * 64 + mt * 16 + l16;
#pragma unroll
    for (int s = 0; s < 2; ++s) {
      offA[mt][s] = ra * 128 + (((s * 4 + quad) ^ (ra & 7)) * 16);
      offB[mt][s] = rb * 128 + (((s * 4 + quad) ^ (rb & 7)) * 16);
    }
  }
  f4 acc[4][4] = {};
  for (int k0 = 0; k0 < K; k0 += 64) {
#pragma unroll
    for (int i = 0; i < 4; ++i) {
      async16(aptr[i] + k0, sA + soff[i]);
      async16(bptr[i] + k0, sB + soff[i]);
    }
    __syncthreads();
#pragma unroll
    for (int s = 0; s < 2; ++s) {
      half8 a[4], b[4];
#pragma unroll
      for (int mt = 0; mt < 4; ++mt) a[mt] = *(const half8*)(sA + offA[mt][s]);
#pragma unroll
      for (int nt = 0; nt < 4; ++nt) b[nt] = *(const half8*)(sB + offB[nt][s]);
#pragma unroll
      for (int mt = 0; mt < 4; ++mt)
#pragma unroll
        for (int nt = 0; nt < 4; ++nt)
          acc[mt][nt] = __builtin_amdgcn_mfma_f32_16x16x32_f16(a[mt], b[nt], acc[mt][nt], 0, 0, 0);
    }
    __syncthreads();
  }
  const float* bias = eb1 + (size_t)e * H_DIM;
  unsigned short* out = EHS + (size_t)e * Brows * H_DIM;
#pragma unroll
  for (int nt = 0; nt < 4; ++nt) {
    int col = n0 + wn * 64 + nt * 16 + l16;
    float bb = bias[col];
#pragma unroll
    for (int mt = 0; mt < 4; ++mt) {
#pragma unroll
      for (int r = 0; r < 4; ++r) {
        int rloc = wm * 64 + mt * 16 + quad * 4 + r;
        float v = fmaxf(acc[mt][nt][r] + bb, 0.f) * sC[rloc];
        out[(size_t)(m0 + rloc) * H_DIM + col] = f2h_bits(v);
      }
    }
  }
}

// ------- expert GEMM2: out = sum_e (ehs_e @ w2_e) + sum_e c_e*eb2_e --------
__global__ __launch_bounds__(256) void k_expert_o(const unsigned short* __restrict__ EHS,
                                                  const unsigned short* __restrict__ W2T,
                                                  const float* __restrict__ combine,
                                                  const float* __restrict__ eb2,
                                                  float* __restrict__ OUT,
                                                  int Brows) {
  constexpr int K = H_DIM;  // 4096
  const int m0 = blockIdx.y * 128, n0 = blockIdx.x * 128;
  __shared__ __align__(16) char smem[32768];
  __shared__ float sC3[3][128];
  char* sA = smem;
  char* sB = smem + 16384;
  const int t = threadIdx.x;
  if (t < 128) {
    sC3[0][t] = combine[(size_t)(m0 + t) * 3 + 0];
    sC3[1][t] = combine[(size_t)(m0 + t) * 3 + 1];
    sC3[2][t] = combine[(size_t)(m0 + t) * 3 + 2];
  }
  int srow[4], sj[4], soff[4];
#pragma unroll
  for (int i = 0; i < 4; ++i) {
    int sa = t + i * 256;
    srow[i] = sa >> 3;
    sj[i] = (sa & 7) ^ (srow[i] & 7);
    soff[i] = sa * 16;
  }
  const int lane = t & 63;
  const int wm = (t >> 6) & 1, wn = t >> 7;
  const int quad = lane >> 4, l16 = lane & 15;
  int offA[4][2], offB[4][2];
#pragma unroll
  for (int mt = 0; mt < 4; ++mt) {
    int ra = wm * 64 + mt * 16 + l16;
    int rb = wn * 64 + mt * 16 + l16;
#pragma unroll
    for (int s = 0; s < 2; ++s) {
      offA[mt][s] = ra * 128 + (((s * 4 + quad) ^ (ra & 7)) * 16);
      offB[mt][s] = rb * 128 + (((s * 4 + quad) ^ (rb & 7)) * 16);
    }
  }
  f4 acc[4][4] = {};
  for (int e = 0; e < 3; ++e) {
    const unsigned short* Ab = EHS + (size_t)e * Brows * H_DIM + (size_t)m0 * K;
    const unsigned short* Bb = W2T + (size_t)e * O_DIM * H_DIM + (size_t)n0 * K;
    const unsigned short* ap[4];
    const unsigned short* bp[4];
#pragma unroll
    for (int i = 0; i < 4; ++i) {
      ap[i] = Ab + (size_t)srow[i] * K + sj[i] * 8;
      bp[i] = Bb + (size_t)srow[i] * K + sj[i] * 8;
    }
    for (int k0 = 0; k0 < K; k0 += 64) {
#pragma unroll
      for (int i = 0; i < 4; ++i) {
        async16(ap[i] + k0, sA + soff[i]);
        async16(bp[i] + k0, sB + soff[i]);
      }
      __syncthreads();
#pragma unroll
      for (int s = 0; s < 2; ++s) {
        half8 a[4], b[4];
#pragma unroll
        for (int mt = 0; mt < 4; ++mt) a[mt] = *(const half8*)(sA + offA[mt][s]);
#pragma unroll
        for (int nt = 0; nt < 4; ++nt) b[nt] = *(const half8*)(sB + offB[nt][s]);
#pragma unroll
        for (int mt = 0; mt < 4; ++mt)
#pragma unroll
          for (int nt = 0; nt < 4; ++nt)
            acc[mt][nt] = __builtin_amdgcn_mfma_f32_16x16x32_f16(a[mt], b[nt], acc[mt][nt], 0, 0, 0);
      }
      __syncthreads();
    }
  }
#pragma unroll
  for (int nt = 0; nt < 4; ++nt) {
    int col = n0 + wn * 64 + nt * 16 + l16;
    float b0 = eb2[col], b1 = eb2[O_DIM + col], b2 = eb2[2 * O_DIM + col];
#pragma unroll
    for (int mt = 0; mt < 4; ++mt) {
#pragma unroll
      for (int r = 0; r < 4; ++r) {
        int rloc = wm * 64 + mt * 16 + quad * 4 + r;
        float v = acc[mt][nt][r] + sC3[0][rloc] * b0 + sC3[1][rloc] * b1 + sC3[2][rloc] * b2;
        OUT[(size_t)(m0 + rloc) * O_DIM + col] = v;
      }
    }
  }
}

extern "C" void kernel_launch(void* const* d_in, const int* in_sizes, int n_in,
                              void* d_out, int out_size, void* d_ws, size_t ws_size,
                              hipStream_t stream) {
  const float* x   = (const float*)d_in[0];
  const float* gw1 = (const float*)d_in[1];
  const float* gb1 = (const float*)d_in[2];
  const float* gw2 = (const float*)d_in[3];
  const float* gb2 = (const float*)d_in[4];
  const float* gw3 = (const float*)d_in[5];
  const float* gb3 = (const float*)d_in[6];
  const float* ew1 = (const float*)d_in[7];
  const float* eb1 = (const float*)d_in[8];
  const float* ew2 = (const float*)d_in[9];
  const float* eb2 = (const float*)d_in[10];
  float* out = (float*)d_out;
  float* gates = out + (size_t)B_ROWS * O_DIM;

  char* ws = (char*)d_ws;
  size_t off = 0;
  auto take = [&](size_t bytes) -> char* {
    char* p = ws + off;
    off += (bytes + 255) & ~(size_t)255;
    return p;
  };
  // fixed region: 67.4 MB
  unsigned short* xh  = (unsigned short*)take((size_t)B_ROWS * D_DIM * 2);        // 16.8 MB
  unsigned short* w1t = (unsigned short*)take((size_t)E_NUM * H_DIM * D_DIM * 2); // 25.2 MB
  unsigned short* w2t = (unsigned short*)take((size_t)E_NUM * O_DIM * H_DIM * 2); // 25.2 MB
  float* comb = (float*)take((size_t)B_ROWS * 3 * 4);                             // 0.1 MB

  // chunked region: sized to whatever workspace remains.
  // per-row bytes: ehs 3*4096*2 + g1 256*4 + h2 128*4 = 26112
  char* rest = ws + off;
  size_t rest_sz = (ws_size > off) ? (ws_size - off) : 0;
  int Bc = (int)((rest_sz / 26112) / 128 * 128);
  if (Bc > 4096) Bc = 4096;
  if (Bc < 128) Bc = 128;  // below this the workspace is fundamentally too small

  unsigned short* ehs = (unsigned short*)rest;
  float* g1 = (float*)(rest + (size_t)E_NUM * Bc * H_DIM * 2);
  float* h2 = (float*)((char*)g1 + (size_t)Bc * 256 * 4);

  // precision-insensitive pre-pass: f16 casts/transposes
  k_cast_x<<<dim3(B_ROWS * D_DIM / (256 * 8)), 256, 0, stream>>>(x, xh);
  k_transpose_cast<<<dim3(H_DIM / 32, D_DIM / 32, E_NUM), 256, 0, stream>>>(ew1, w1t, D_DIM, H_DIM);
  k_transpose_cast<<<dim3(O_DIM / 32, H_DIM / 32, E_NUM), 256, 0, stream>>>(ew2, w2t, H_DIM, O_DIM);

  for (int row0 = 0; row0 < B_ROWS; row0 += Bc) {
    int rows = B_ROWS - row0;
    if (rows > Bc) rows = Bc;
    // gating in fp32 (top-k selection must track the fp32 reference)
    k_gemm_f32<<<dim3(256 / 64, rows / 64), 256, 0, stream>>>(
        x + (size_t)row0 * D_DIM, gw1, gb1, g1, 256, D_DIM);
    k_gemm_f32<<<dim3(128 / 64, rows / 64), 256, 0, stream>>>(
        g1, gw2, gb2, h2, 128, 256);
    k_gate_topk<<<dim3(rows / 4), 256, 0, stream>>>(
        h2, gw3, gb3, gates + (size_t)row0 * 3, comb + (size_t)row0 * 3);
    // experts in f16 MFMA
    k_expert_h<<<dim3(H_DIM / 128, rows / 128, E_NUM), 256, 0, stream>>>(
        xh + (size_t)row0 * D_DIM, w1t, comb + (size_t)row0 * 3, eb1, ehs, rows);
    k_expert_o<<<dim3(O_DIM / 128, rows / 128), 256, 0, stream>>>(
        ehs, w2t, comb + (size_t)row0 * 3, eb2, out + (size_t)row0 * O_DIM, rows);
  }
}